// Round 5
// baseline (71.181 us; speedup 1.0000x reference)
//
#include <hip/hip_runtime.h>

// Problem constants: IMG=512, CUT_SIZE=224, CUTN=64, B=4, C=3
constexpr int S   = 224;
constexpr int Wim = 512;
constexpr int Him = 512;
constexpr int PLANES = 12;                 // B*C
constexpr int SB   = 32;                   // source rows per band
constexpr int NBANDS = Him / SB;           // 16
constexpr int NGRP = 4;                    // cutouts per block
constexpr int GROUPS = 64 / NGRP;          // 16
constexpr int TILES = PLANES * NBANDS;     // 192 (plane,band) tiles
constexpr int TPX   = TILES / 8;           // 24 tiles per XCD -> 1.5 planes each
constexpr int LOCALS = TPX * GROUPS;       // 384
constexpr int GRID   = 8 * LOCALS;         // 3072
constexpr int ROWPAD = Wim + 4;            // 516 floats; pad cols zeroed (weight-0 reads)

__device__ __forceinline__ void load_lds16(const float* g, float* l) {
    __builtin_amdgcn_global_load_lds(
        (const __attribute__((address_space(1))) void*)g,
        (__attribute__((address_space(3))) void*)l,
        16, 0, 0);
}

// iy0 exactly as the reference computes it (frac-before-clamp handled at use site)
__device__ __forceinline__ int iy0_of(int i, float scale, int sz) {
    const float sy = fmaxf(scale * ((float)i + 0.5f) - 0.5f, 0.0f);
    return min((int)floorf(sy), sz - 1);
}

// smallest i in [0,224] with iy0_of(i) >= P  (exact-predicate fix-up)
__device__ __forceinline__ int first_ge(float scale, int sz, int P) {
    if (P <= 0) return 0;
    if (P > sz - 1) return S;
    float c = ((float)P + 0.5f) / scale - 0.5f;
    int i = (int)ceilf(fminf(fmaxf(c, 0.0f), (float)S));
    while (i > 0 && iy0_of(i - 1, scale, sz) >= P) --i;
    while (i < S && iy0_of(i, scale, sz) < P) ++i;
    return i;
}

__global__ __launch_bounds__(512) void cutouts_kernel(
    const float* __restrict__ x,
    const int*   __restrict__ sizes,
    const int*   __restrict__ offx,
    const int*   __restrict__ offy,
    float*       __restrict__ out)
{
    __shared__ float lds[SB + 1][ROWPAD];            // 33 x 516 floats ~ 66.5 KiB

    const int lane = threadIdx.x & 63;
    const int wv   = threadIdx.x >> 6;               // 0..7

    // decode: XCD-affine (plane,band) tiles, group-major per XCD
    const int xcd   = blockIdx.x & 7;
    const int local = blockIdx.x >> 3;               // 0..383
    const int g     = local / TPX;                   // cutout group 0..15
    const int tk    = local - g * TPX;               // tile-in-xcd 0..23
    const int t     = xcd * TPX + tk;                // 0..191
    const int pi    = t >> 4;                        // plane 0..11
    const int b     = t & (NBANDS - 1);              // band 0..15

    // zero the pad columns (hit only by weight-0 neighbor reads)
    if (threadIdx.x < (SB + 1) * 4)
        lds[threadIdx.x >> 2][Wim + (threadIdx.x & 3)] = 0.0f;

    // stage band: 33 rows x 512 floats = 66 chunks of 256 floats (1 KB DMA each)
    const float* plane = x + (size_t)pi * (Him * Wim);
    for (int c = wv; c < (SB + 1) * 2; c += 8) {
        const int row  = c >> 1, half = c & 1;
        const int srow = min(SB * b + row, Him - 1);  // row 512 never read; avoid OOB
        load_lds16(plane + (size_t)srow * Wim + half * 256 + lane * 4,
                   &lds[row][half * 256]);
    }
    asm volatile("s_waitcnt vmcnt(0)" ::: "memory");
    __syncthreads();

    #pragma unroll
    for (int nn = 0; nn < NGRP; ++nn) {
        const int n  = g * NGRP + nn;
        const int sz = sizes[n];
        const int oy = offy[n];
        const int ox = offx[n];
        const float scale = (float)sz * (1.0f / (float)S);

        const int L = SB * b - oy;                   // band range rel. to cutout
        const int R = L + SB;
        const int i_lo = first_ge(scale, sz, L);     // bands partition [0,224)
        const int i_hi = first_ge(scale, sz, R);

        float* oplane = out + (size_t)(n * PLANES + pi) * (S * S);

        for (int i = i_lo + wv; i < i_hi; i += 8) {
            const float sy  = fmaxf(scale * ((float)i + 0.5f) - 0.5f, 0.0f);
            const float fiy = floorf(sy);
            const float fy  = sy - fiy;              // frac BEFORE clamp (reference)
            const int   iy0 = min((int)fiy, sz - 1);
            const int   iy1 = min(iy0 + 1, sz - 1);
            const float* l0 = &lds[iy0 - L][0];      // rel rows in [0,32]
            const float* l1 = &lds[iy1 - L][0];
            float* orow = oplane + (size_t)i * S;

            #pragma unroll
            for (int r = 0; r < 4; ++r) {
                const int px = r * 64 + lane;        // 224 = 3*64 + 32
                if (r < 3 || px < S) {
                    const float sx  = fmaxf(scale * ((float)px + 0.5f) - 0.5f, 0.0f);
                    const float fix = floorf(sx);
                    const float fx  = sx - fix;
                    const int   ix  = min((int)fix, sz - 1) + ox;
                    // ix+1 may reach col 512 only with fx==0 -> pad col zeroed
                    const float v00 = l0[ix], v01 = l0[ix + 1];
                    const float v10 = l1[ix], v11 = l1[ix + 1];
                    const float top = v00 + (v01 - v00) * fx;
                    const float bot = v10 + (v11 - v10) * fx;
                    orow[px] = top + (bot - top) * fy;
                }
            }
        }
    }
}

extern "C" void kernel_launch(void* const* d_in, const int* in_sizes, int n_in,
                              void* d_out, int out_size, void* d_ws, size_t ws_size,
                              hipStream_t stream) {
    const float* x     = (const float*)d_in[0];
    const int*   sizes = (const int*)d_in[1];
    const int*   offx  = (const int*)d_in[2];
    const int*   offy  = (const int*)d_in[3];
    float* out = (float*)d_out;

    cutouts_kernel<<<GRID, 512, 0, stream>>>(x, sizes, offx, offy, out);
}

// Round 7
// 58.666 us; speedup vs baseline: 1.2133x; 1.2133x over previous
//
#include <hip/hip_runtime.h>
#include <stdint.h>

// Problem constants: IMG=512, CUT_SIZE=224, CUTN=64, B=4, C=3; sizes in [224,511]
constexpr int S   = 224;
constexpr int Wim = 512;
constexpr int Him = 512;
constexpr int PLANES = 12;                          // B*C
constexpr int N   = 64;
constexpr int HROWS = S / 2;                        // 112
constexpr int ROWS_PER_HP  = N * HROWS;             // 7168
constexpr int ROWS_PER_XCD = 3 * ROWS_PER_HP;       // 21504 (24 half-planes / 8 XCDs)
constexpr int WPB = 4;                              // waves/block, 1 output row each
constexpr int BLOCKS_PER_XCD = ROWS_PER_XCD / WPB;  // 5376
constexpr int GRID = 8 * BLOCKS_PER_XCD;            // 43008
constexpr uint32_t XBYTES = (uint32_t)PLANES * Him * Wim * 4u;  // 12,582,912

typedef float    f32x2   __attribute__((ext_vector_type(2)));
typedef uint32_t srsrc_t __attribute__((ext_vector_type(4)));   // SGPR quad (HK idiom)

// SRSRC buffer loads (T8): one dwordx2 regardless of 4B alignment phase,
// HW bounds-check via num_records (OOB load returns 0, never faults).
__device__ __forceinline__ f32x2 bload2_r0(srsrc_t srd, uint32_t voff) {
    f32x2 d;
    asm volatile("buffer_load_dwordx2 %0, %1, %2, 0 offen"
                 : "=v"(d) : "v"(voff), "s"(srd) : "memory");
    return d;
}
__device__ __forceinline__ f32x2 bload2_r1(srsrc_t srd, uint32_t voff) {
    f32x2 d;  // +2048 B = next source row (W=512 floats)
    asm volatile("buffer_load_dwordx2 %0, %1, %2, 0 offen offset:2048"
                 : "=v"(d) : "v"(voff), "s"(srd) : "memory");
    return d;
}

__global__ __launch_bounds__(256) void cutouts_kernel(
    const float* __restrict__ x,
    const int*   __restrict__ sizes,
    const int*   __restrict__ offx,
    const int*   __restrict__ offy,
    float*       __restrict__ out)
{
    const int lane = threadIdx.x & 63;
    const int wv   = threadIdx.x >> 6;

    // XCD-affine half-plane ownership (R1), one output row per wave (1 px/lane)
    const int k     = blockIdx.x & 7;
    const int w_row = (blockIdx.x >> 3) * WPB + wv;   // [0, 21504)
    const int hpsel = w_row / ROWS_PER_HP;
    const int rem   = w_row - hpsel * ROWS_PER_HP;
    const int n     = rem / HROWS;                    // cutout
    const int il    = rem - n * HROWS;
    const int hp    = k + (hpsel << 3);               // half-plane 0..23
    const int pi    = hp >> 1;                        // plane = b*C+c
    const int i     = (hp & 1) * HROWS + il;          // output row

    const int   sz    = sizes[n];
    const float scale = (float)sz / (float)S;
    const int   oy    = offy[n];
    const int   ox    = offx[n];

    // vertical: frac BEFORE clamp (reference); clamp only engages where frac==0,
    // so a=min(iy0,sz-2), fy~=fy+(iy0-a) is exact and keeps both rows in-bounds
    const float sy  = fmaxf(scale * ((float)i + 0.5f) - 0.5f, 0.0f);
    const float fiy = floorf(sy);
    const int   iy0 = (int)fiy;
    const int   ay  = min(iy0, sz - 2);
    const float fy  = (sy - fiy) + (float)(iy0 - ay);

    // byte offset of (plane pi, row oy+ay, col ox)
    const uint32_t rowbase =
        ((uint32_t)pi * (uint32_t)(Him * Wim) + (uint32_t)(oy + ay) * Wim + (uint32_t)ox) * 4u;

    srsrc_t srd;
    {
        const uint64_t a = (uint64_t)(uintptr_t)x;
        srd.x = (uint32_t)a;
        srd.y = (uint32_t)(a >> 32);                  // stride=0
        srd.z = XBYTES;                               // num_records in bytes
        srd.w = 0x00020000u;                          // raw dword access
    }

    // phase 1: issue all 8 gathers (4 px-iters x 2 rows)
    float fxv[4];
    f32x2 p0[4], p1[4];
    #pragma unroll
    for (int r = 0; r < 4; ++r) {
        const int   px  = r * 64 + lane;
        const float sx  = fmaxf(scale * ((float)px + 0.5f) - 0.5f, 0.0f);
        const float fix = floorf(sx);
        const int   ix0 = (int)fix;
        const int   a   = min(ix0, sz - 2);           // pair [a, a+1] always in-bounds
        fxv[r] = (sx - fix) + (float)(ix0 - a);       // exact (frac==0 when clamped)
        const uint32_t voff = rowbase + (uint32_t)a * 4u;
        p0[r] = bload2_r0(srd, voff);                 // v00, v01
        p1[r] = bload2_r1(srd, voff);                 // v10, v11
    }
    asm volatile("s_waitcnt vmcnt(0)" ::: "memory");
    __builtin_amdgcn_sched_barrier(0);                // rule 18: no hoist past asm wait

    // phase 2: blend + coalesced stores
    float* orow = out + (size_t)(n * PLANES + pi) * (S * S) + (size_t)i * S;
    #pragma unroll
    for (int r = 0; r < 4; ++r) {
        const int px = r * 64 + lane;
        if (r < 3 || lane < 32) {                     // 224 = 3*64 + 32
            const float h0 = p0[r].x + (p0[r].y - p0[r].x) * fxv[r];
            const float h1 = p1[r].x + (p1[r].y - p1[r].x) * fxv[r];
            orow[px] = h0 + (h1 - h0) * fy;
        }
    }
}

extern "C" void kernel_launch(void* const* d_in, const int* in_sizes, int n_in,
                              void* d_out, int out_size, void* d_ws, size_t ws_size,
                              hipStream_t stream) {
    const float* x     = (const float*)d_in[0];
    const int*   sizes = (const int*)d_in[1];
    const int*   offx  = (const int*)d_in[2];
    const int*   offy  = (const int*)d_in[3];
    float* out = (float*)d_out;

    cutouts_kernel<<<GRID, 256, 0, stream>>>(x, sizes, offx, offy, out);
}

// Round 8
// 43.259 us; speedup vs baseline: 1.6455x; 1.3562x over previous
//
#include <hip/hip_runtime.h>
#include <stdint.h>

// Problem constants: IMG=512, CUT_SIZE=224, CUTN=64, B=4, C=3; sizes in [224,511]
constexpr int S   = 224;
constexpr int Wim = 512;
constexpr int PLANES = 12;                           // B*C
constexpr int N   = 64;
constexpr int HROWS = S / 2;                         // 112
constexpr int PAIRS_PER_HP  = N * (HROWS / 2);       // 3584 row-pairs per half-plane
constexpr int PAIRS_PER_XCD = 3 * PAIRS_PER_HP;      // 10752 (24 half-planes / 8 XCDs)
constexpr int WPB   = 4;                             // waves/block, 1 row-pair each
constexpr int BLOCKS_PER_XCD = PAIRS_PER_XCD / WPB;  // 2688
constexpr int GRID  = 8 * BLOCKS_PER_XCD;            // 21504
constexpr int BUFD  = 544;                           // dwords per row buffer (512 + pad)

typedef float f32x4 __attribute__((ext_vector_type(4)));

__device__ __forceinline__ void vparams(int i, float scale, int sz,
                                        int& ay, float& fy) {
    // frac BEFORE clamp (reference); clamp engages only where frac==0 -> exact
    const float sy  = fmaxf(scale * ((float)i + 0.5f) - 0.5f, 0.0f);
    const float fiy = floorf(sy);
    const int   iy0 = (int)fiy;
    ay = min(iy0, sz - 2);                  // rows [ay, ay+1] always in-image
    fy = (sy - fiy) + (float)(iy0 - ay);    // 1.0 exactly in the clamped case
}

// horizontal pass: 4 adjacent px per lane from the blended LDS row, 1 dwordx4 store
__device__ __forceinline__ void hpass(const float* buf, int shift, float scale,
                                      int lane, float* orow) {
    if (lane < 56) {                        // 224 = 56 lanes x 4 px
        const int pxb = 4 * lane;
        f32x4 o;
        #pragma unroll
        for (int r = 0; r < 4; ++r) {
            const float sx  = fmaxf(scale * ((float)(pxb + r) + 0.5f) - 0.5f, 0.0f);
            const float fix = floorf(sx);
            const float fx  = sx - fix;     // ix0 <= sz-1 always (proven for sz>=224)
            const int   d   = shift + (int)fix;
            const float v0 = buf[d], v1 = buf[d + 1];   // weight-0 OOB slots are zeroed
            o[r] = v0 + (v1 - v0) * fx;
        }
        *(f32x4*)(orow + pxb) = o;
    }
}

__global__ __launch_bounds__(256) void cutouts_kernel(
    const float* __restrict__ x,
    const int*   __restrict__ sizes,
    const int*   __restrict__ offx,
    const int*   __restrict__ offy,
    float*       __restrict__ out)
{
    __shared__ float lds[WPB][2][BUFD];              // ~17 KiB/block

    const int lane = threadIdx.x & 63;
    const int wv   = threadIdx.x >> 6;

    // XCD-affine half-plane ownership (as R3), one adjacent row-PAIR per wave
    const int k     = blockIdx.x & 7;
    const int pair  = (blockIdx.x >> 3) * WPB + wv;
    const int hpsel = pair / PAIRS_PER_HP;
    const int rem   = pair - hpsel * PAIRS_PER_HP;
    const int n     = rem / (HROWS / 2);             // cutout
    const int mp    = rem - n * (HROWS / 2);
    const int hp    = k + (hpsel << 3);              // half-plane 0..23
    const int pi    = hp >> 1;                       // plane = b*C+c
    const int i0    = (hp & 1) * HROWS + 2 * mp;     // first output row

    const int   sz    = sizes[n];
    const float scale = (float)sz / (float)S;
    const int   oy    = offy[n];
    const int   ox    = offx[n];
    const float* plane = x + (size_t)pi * (Wim * Wim);

    // column window: float4 index base4..base4+127 covers all needed cols
    const int base4  = ox >> 2;
    const int shift  = ox & 3;
    const int lastc4 = 127 - base4;                  // last in-image col4 offset
    const int K4     = (shift + sz + 5) >> 2;        // float4s needed (incl. wt-0 tail)
    const bool hi    = K4 > 64;                      // wave-uniform

    int ay0, ay1; float fy0, fy1;
    vparams(i0,     scale, sz, ay0, fy0);
    vparams(i0 + 1, scale, sz, ay1, fy1);

    const int cA = min(lane, lastc4);                // clamped (dup loads, same line)
    const int cB = min(lane + 64, lastc4);

    const float* rA = plane + (size_t)(oy + ay0) * Wim + 4 * base4;
    const float* rB = plane + (size_t)(oy + ay1) * Wim + 4 * base4;

    // issue ALL global loads up front (both rows of the pair)
    f32x4 p00 = *(const f32x4*)(rA + 4 * cA);
    f32x4 p01 = *(const f32x4*)(rA + Wim + 4 * cA);
    f32x4 p10 = *(const f32x4*)(rB + 4 * cA);
    f32x4 p11 = *(const f32x4*)(rB + Wim + 4 * cA);
    f32x4 q00{}, q01{}, q10{}, q11{};
    if (hi) {
        q00 = *(const f32x4*)(rA + 4 * cB);
        q01 = *(const f32x4*)(rA + Wim + 4 * cB);
        q10 = *(const f32x4*)(rB + 4 * cB);
        q11 = *(const f32x4*)(rB + Wim + 4 * cB);
    }

    float* buf0 = &lds[wv][0][0];
    float* buf1 = &lds[wv][1][0];
    float* obase = out + (size_t)(n * PLANES + pi) * (S * S);

    // row 0: vertical blend in regs -> LDS -> horizontal -> store
    {
        f32x4 w = p00 + (p01 - p00) * fy0;
        if (lane > lastc4) w = f32x4{0.f, 0.f, 0.f, 0.f};   // OOB cols: zero (wt-0 reads)
        *(f32x4*)(buf0 + 4 * lane) = w;
        if (hi) {
            f32x4 wh = q00 + (q01 - q00) * fy0;
            if (lane + 64 > lastc4) wh = f32x4{0.f, 0.f, 0.f, 0.f};
            *(f32x4*)(buf0 + 4 * (lane + 64)) = wh;
        }
    }
    hpass(buf0, shift, scale, lane, obase + (size_t)i0 * S);

    // row 1
    {
        f32x4 w = p10 + (p11 - p10) * fy1;
        if (lane > lastc4) w = f32x4{0.f, 0.f, 0.f, 0.f};
        *(f32x4*)(buf1 + 4 * lane) = w;
        if (hi) {
            f32x4 wh = q10 + (q11 - q10) * fy1;
            if (lane + 64 > lastc4) wh = f32x4{0.f, 0.f, 0.f, 0.f};
            *(f32x4*)(buf1 + 4 * (lane + 64)) = wh;
        }
    }
    hpass(buf1, shift, scale, lane, obase + (size_t)(i0 + 1) * S);
}

extern "C" void kernel_launch(void* const* d_in, const int* in_sizes, int n_in,
                              void* d_out, int out_size, void* d_ws, size_t ws_size,
                              hipStream_t stream) {
    const float* x     = (const float*)d_in[0];
    const int*   sizes = (const int*)d_in[1];
    const int*   offx  = (const int*)d_in[2];
    const int*   offy  = (const int*)d_in[3];
    float* out = (float*)d_out;

    cutouts_kernel<<<GRID, 256, 0, stream>>>(x, sizes, offx, offy, out);
}

// Round 9
// 42.112 us; speedup vs baseline: 1.6903x; 1.0272x over previous
//
#include <hip/hip_runtime.h>
#include <stdint.h>

// Problem constants: IMG=512, CUT_SIZE=224, CUTN=64, B=4, C=3; sizes in [224,511]
constexpr int S   = 224;
constexpr int Wim = 512;
constexpr int PLANES = 12;                           // B*C
constexpr int N   = 64;
constexpr int HROWS = S / 2;                         // 112
constexpr int PAIRS_PER_HP  = N * (HROWS / 2);       // 3584 row-pairs per half-plane
constexpr int PAIRS_PER_XCD = 3 * PAIRS_PER_HP;      // 10752 (24 half-planes / 8 XCDs)
constexpr int WPB   = 4;                             // waves/block, 1 row-pair each
constexpr int BLOCKS_PER_XCD = PAIRS_PER_XCD / WPB;  // 2688
constexpr int GRID  = 8 * BLOCKS_PER_XCD;            // 21504
constexpr int BUFD  = 544;                           // dwords per row buffer (512 + pad)

typedef float f32x4 __attribute__((ext_vector_type(4)));

__device__ __forceinline__ void vparams(int i, float scale, int sz,
                                        int& ay, float& fy) {
    // frac BEFORE clamp (reference); clamp engages only where frac==0 -> exact
    const float sy  = fmaxf(scale * ((float)i + 0.5f) - 0.5f, 0.0f);
    const float fiy = floorf(sy);
    const int   iy0 = (int)fiy;
    ay = min(iy0, sz - 2);                  // rows [ay, ay+1] always in-image
    fy = (sy - fiy) + (float)(iy0 - ay);    // 1.0 exactly in the clamped case
}

__global__ __launch_bounds__(256) void cutouts_kernel(
    const float* __restrict__ x,
    const int*   __restrict__ sizes,
    const int*   __restrict__ offx,
    const int*   __restrict__ offy,
    float*       __restrict__ out)
{
    __shared__ float lds[WPB][2][BUFD];              // ~17 KiB/block

    const int lane = threadIdx.x & 63;
    const int wv   = threadIdx.x >> 6;

    // XCD-affine half-plane ownership, one adjacent output row-PAIR per wave
    const int k     = blockIdx.x & 7;
    const int pair  = (blockIdx.x >> 3) * WPB + wv;
    const int hpsel = pair / PAIRS_PER_HP;
    const int rem   = pair - hpsel * PAIRS_PER_HP;
    const int n     = rem / (HROWS / 2);             // cutout
    const int mp    = rem - n * (HROWS / 2);
    const int hp    = k + (hpsel << 3);              // half-plane 0..23
    const int pi    = hp >> 1;                       // plane = b*C+c
    const int i0    = (hp & 1) * HROWS + 2 * mp;     // first output row

    const int   sz    = sizes[n];
    const float scale = (float)sz / (float)S;
    const int   oy    = offy[n];
    const int   ox    = offx[n];
    const float* plane = x + (size_t)pi * (Wim * Wim);

    // column window: float4 index base4..base4+127 covers all needed cols
    const int base4  = ox >> 2;
    const int shift  = ox & 3;
    const int lastc4 = 127 - base4;                  // last in-image col4 offset
    const int K4     = (shift + sz + 5) >> 2;        // float4s needed (incl. wt-0 tail)
    const bool hi    = K4 > 64;                      // wave-uniform

    int ay0, ay1; float fy0, fy1;
    vparams(i0,     scale, sz, ay0, fy0);
    vparams(i0 + 1, scale, sz, ay1, fy1);

    const int cA = min(lane, lastc4);                // clamped (dup loads, same line)
    const int cB = min(lane + 64, lastc4);

    const float* rA = plane + (size_t)(oy + ay0) * Wim + 4 * base4;
    const float* rB = plane + (size_t)(oy + ay1) * Wim + 4 * base4;

    // issue ALL global loads up front (both rows of the pair)
    f32x4 p00 = *(const f32x4*)(rA + 4 * cA);
    f32x4 p01 = *(const f32x4*)(rA + Wim + 4 * cA);
    f32x4 p10 = *(const f32x4*)(rB + 4 * cA);
    f32x4 p11 = *(const f32x4*)(rB + Wim + 4 * cA);
    f32x4 q00{}, q01{}, q10{}, q11{};
    if (hi) {
        q00 = *(const f32x4*)(rA + 4 * cB);
        q01 = *(const f32x4*)(rA + Wim + 4 * cB);
        q10 = *(const f32x4*)(rB + 4 * cB);
        q11 = *(const f32x4*)(rB + Wim + 4 * cB);
    }

    float* buf0 = &lds[wv][0][0];
    float* buf1 = &lds[wv][1][0];

    // vertical blend in regs -> LDS (both rows before any read: one lgkm drain)
    {
        f32x4 w0 = p00 + (p01 - p00) * fy0;
        f32x4 w1 = p10 + (p11 - p10) * fy1;
        if (lane > lastc4) { w0 = f32x4{0.f,0.f,0.f,0.f}; w1 = f32x4{0.f,0.f,0.f,0.f}; }
        *(f32x4*)(buf0 + 4 * lane) = w0;
        *(f32x4*)(buf1 + 4 * lane) = w1;
        if (hi) {
            f32x4 h0 = q00 + (q01 - q00) * fy0;
            f32x4 h1 = q10 + (q11 - q10) * fy1;
            if (lane + 64 > lastc4) { h0 = f32x4{0.f,0.f,0.f,0.f}; h1 = f32x4{0.f,0.f,0.f,0.f}; }
            *(f32x4*)(buf0 + 4 * (lane + 64)) = h0;
            *(f32x4*)(buf1 + 4 * (lane + 64)) = h1;
        }
    }

    // horizontal pass: stride-1 lane mapping (px = r*64+lane -> lane LDS stride
    // = scale in [1,2.28] floats -> ~2-way bank aliasing, near-free per m136);
    // d/fx computed ONCE per r, reused for both rows of the pair
    float* orow0 = out + (size_t)(n * PLANES + pi) * (S * S) + (size_t)i0 * S;
    float* orow1 = orow0 + S;
    #pragma unroll
    for (int r = 0; r < 4; ++r) {
        const int px = r * 64 + lane;
        if (r < 3 || lane < 32) {                    // 224 = 3*64 + 32
            const float sx  = fmaxf(scale * ((float)px + 0.5f) - 0.5f, 0.0f);
            const float fix = floorf(sx);
            const float fx  = sx - fix;              // ix0 <= sz-1 (proven, sz>=224)
            const int   d   = shift + (int)fix;
            const float a0 = buf0[d], a1 = buf0[d + 1];   // wt-0 OOB slots zeroed
            const float c0 = buf1[d], c1 = buf1[d + 1];   // same addr + BUFD*4 imm
            orow0[px] = a0 + (a1 - a0) * fx;
            orow1[px] = c0 + (c1 - c0) * fx;
        }
    }
}

extern "C" void kernel_launch(void* const* d_in, const int* in_sizes, int n_in,
                              void* d_out, int out_size, void* d_ws, size_t ws_size,
                              hipStream_t stream) {
    const float* x     = (const float*)d_in[0];
    const int*   sizes = (const int*)d_in[1];
    const int*   offx  = (const int*)d_in[2];
    const int*   offy  = (const int*)d_in[3];
    float* out = (float*)d_out;

    cutouts_kernel<<<GRID, 256, 0, stream>>>(x, sizes, offx, offy, out);
}

// Round 10
// 40.711 us; speedup vs baseline: 1.7484x; 1.0344x over previous
//
#include <hip/hip_runtime.h>
#include <stdint.h>

// Problem constants: IMG=512, CUT_SIZE=224, CUTN=64, B=4, C=3; sizes in [224,511]
constexpr int S   = 224;
constexpr int Wim = 512;
constexpr int PLANES = 12;                            // B*C
constexpr int N   = 64;
constexpr int HROWS = S / 2;                          // 112 rows per half
constexpr int QROWS = 8;                              // rows per wave = 4 pairs
constexpr int QUADS_PER_HALF = HROWS / QROWS;         // 14
constexpr int QUADS_PER_HP   = N * QUADS_PER_HALF;    // 896 (per half-plane)
constexpr int QUADS_PER_XCD  = 3 * QUADS_PER_HP;      // 2688 (24 hp / 8 XCDs)
constexpr int WPB = 4;
constexpr int BLOCKS_PER_XCD = QUADS_PER_XCD / WPB;   // 672
constexpr int GRID = 8 * BLOCKS_PER_XCD;              // 5376
constexpr int BUFD = 520;                             // 512 cols + zero pad @512

typedef float f32x4 __attribute__((ext_vector_type(4)));

__device__ __forceinline__ void vparams(int i, float scale, int sz,
                                        int& ay, float& fy) {
    // frac BEFORE clamp (reference); clamp engages only where frac==0 -> exact
    const float sy  = fmaxf(scale * ((float)i + 0.5f) - 0.5f, 0.0f);
    const float fiy = floorf(sy);
    const int   iy0 = (int)fiy;
    ay = min(iy0, sz - 2);                  // rows [ay, ay+1] always in-image
    fy = (sy - fiy) + (float)(iy0 - ay);    // exactly 1.0 in the clamped case
}

__global__ __launch_bounds__(256, 4) void cutouts_kernel(
    const float* __restrict__ x,
    const int*   __restrict__ sizes,
    const int*   __restrict__ offx,
    const int*   __restrict__ offy,
    float*       __restrict__ out)
{
    __shared__ float lds[WPB][2][BUFD];               // ~16.6 KiB/block, wave-private

    const int lane = threadIdx.x & 63;
    const int wv   = threadIdx.x >> 6;

    // XCD-affine half-plane ownership; one wave = 8 rows (4 pairs) of one cutout
    const int k     = blockIdx.x & 7;
    const int quad  = (blockIdx.x >> 3) * WPB + wv;   // [0, 2688)
    const int hpsel = quad / QUADS_PER_HP;            // 0..2
    const int rem   = quad - hpsel * QUADS_PER_HP;    // [0, 896)
    const int n     = rem / QUADS_PER_HALF;           // cutout
    const int qq    = rem - n * QUADS_PER_HALF;       // 0..13
    const int hp    = k + (hpsel << 3);               // half-plane 0..23
    const int pi    = hp >> 1;                        // plane = b*C+c
    const int i0    = (hp & 1) * HROWS + qq * QROWS;  // first of 8 output rows

    const int   sz    = sizes[n];
    const int   oy    = offy[n];
    const int   ox    = offx[n];
    const float scale = (float)sz / (float)S;
    const float* plane = x + (size_t)pi * (Wim * Wim);
    float* obase = out + (size_t)(n * PLANES + pi) * (S * S);

    // horizontal params ONCE for all 8 rows (same n -> same sz/ox)
    int dd[4]; float fx[4];
    #pragma unroll
    for (int r = 0; r < 4; ++r) {
        const int   px = r * 64 + lane;
        const float sx = fmaxf(scale * ((float)px + 0.5f) - 0.5f, 0.0f);
        const float fi = floorf(sx);
        fx[r] = sx - fi;                              // ix0 <= sz-1 (sz>=224)
        dd[r] = ox + (int)fi;                         // dd+1 <= ox+sz <= 512
    }

    float* b0 = &lds[wv][0][0];
    float* b1 = &lds[wv][1][0];
    if (lane < 2) (lane ? b1 : b0)[512] = 0.0f;       // wt-0 neighbor slot

    // 2-deep register-staged pipeline over 4 row-pairs, counted vmcnt (never 0)
    f32x4 st[2][8];                                   // staging, static-indexed
    int   ayv[2][2]; float fyv[2][2];

    #define ISSUE(p, par)                                                     \
    {                                                                         \
        vparams(i0 + 2*(p),     scale, sz, ayv[par][0], fyv[par][0]);         \
        vparams(i0 + 2*(p) + 1, scale, sz, ayv[par][1], fyv[par][1]);         \
        const float* rA = plane + (size_t)(oy + ayv[par][0]) * Wim;           \
        const float* rB = plane + (size_t)(oy + ayv[par][1]) * Wim;           \
        st[par][0] = *(const f32x4*)(rA + 4*lane);                            \
        st[par][1] = *(const f32x4*)(rA + 256 + 4*lane);                      \
        st[par][2] = *(const f32x4*)(rA + Wim + 4*lane);                      \
        st[par][3] = *(const f32x4*)(rA + Wim + 256 + 4*lane);                \
        st[par][4] = *(const f32x4*)(rB + 4*lane);                            \
        st[par][5] = *(const f32x4*)(rB + 256 + 4*lane);                      \
        st[par][6] = *(const f32x4*)(rB + Wim + 4*lane);                      \
        st[par][7] = *(const f32x4*)(rB + Wim + 256 + 4*lane);                \
    }

    ISSUE(0, 0);                                      // prologue

    #pragma unroll
    for (int j = 0; j < 4; ++j) {
        const int par = j & 1;
        if (j < 3) ISSUE(j + 1, (j + 1) & 1);

        // wait pair j's 8 loads (in-order completion): outstanding after them =
        // j==0: L1(8); j==1,2: S(7)+L(8)=15; j==3: S(7)
        if (j == 0)      asm volatile("s_waitcnt vmcnt(8)"  ::: "memory");
        else if (j < 3)  asm volatile("s_waitcnt vmcnt(15)" ::: "memory");
        else             asm volatile("s_waitcnt vmcnt(7)"  ::: "memory");

        // vertical blend in regs -> wave-private LDS rows (full width)
        {
            f32x4 w;
            w = st[par][0] + (st[par][2] - st[par][0]) * fyv[par][0];
            *(f32x4*)(b0 + 4*lane) = w;
            w = st[par][1] + (st[par][3] - st[par][1]) * fyv[par][0];
            *(f32x4*)(b0 + 256 + 4*lane) = w;
            w = st[par][4] + (st[par][6] - st[par][4]) * fyv[par][1];
            *(f32x4*)(b1 + 4*lane) = w;
            w = st[par][5] + (st[par][7] - st[par][5]) * fyv[par][1];
            *(f32x4*)(b1 + 256 + 4*lane) = w;
        }

        // horizontal lerp + coalesced stores (fx/dd hoisted, reused both rows)
        float* o0 = obase + (size_t)(i0 + 2*j) * S;
        float* o1 = o0 + S;
        #pragma unroll
        for (int r = 0; r < 4; ++r) {
            const int px = r * 64 + lane;
            if (r < 3 || lane < 32) {                 // 224 = 3*64 + 32
                const int   d = dd[r];
                const float f = fx[r];
                const float a0 = b0[d], a1 = b0[d + 1];   // pad@512 zeroed, wt-0
                const float c0 = b1[d], c1 = b1[d + 1];
                o0[px] = a0 + (a1 - a0) * f;
                o1[px] = c0 + (c1 - c0) * f;
            }
        }
    }
    #undef ISSUE
}

extern "C" void kernel_launch(void* const* d_in, const int* in_sizes, int n_in,
                              void* d_out, int out_size, void* d_ws, size_t ws_size,
                              hipStream_t stream) {
    const float* x     = (const float*)d_in[0];
    const int*   sizes = (const int*)d_in[1];
    const int*   offx  = (const int*)d_in[2];
    const int*   offy  = (const int*)d_in[3];
    float* out = (float*)d_out;

    cutouts_kernel<<<GRID, 256, 0, stream>>>(x, sizes, offx, offy, out);
}